// Round 16
// baseline (5709.561 us; speedup 1.0000x reference)
//
#include <hip/hip_runtime.h>

// MusicVAE forward. B=256, T=128, NC=96, H=512, G=1536, NB=32, CPB=4.
// All inputs f32; all outputs f32. bf16 MFMA compute, f32 state/accumulate.
// R15 structure. Sequential rows=256 steps use gruL_k: barrier-free direct
// global->MFMA-fragment loads, 2x2 (row-half x K-half) waves, 512 blocks
// (2/CU), single end-of-kernel reduction barrier. Decoder keeps gru_k.

#define BB   256
#define TT   128
#define NCC  96
#define HDIM 512
#define GG   1536
#define NBB  32
#define CPBB 4

typedef __attribute__((ext_vector_type(4))) float f32x4;
typedef __attribute__((ext_vector_type(8))) short bf16x8;
typedef unsigned short ushort_t;

__device__ __forceinline__ unsigned short f2b(float x) {
  unsigned int u = __builtin_bit_cast(unsigned int, x);
  u += 0x7fff + ((u >> 16) & 1);
  return (unsigned short)(u >> 16);
}
__device__ __forceinline__ float b2f(unsigned short h) {
  unsigned int u = ((unsigned int)h) << 16;
  return __builtin_bit_cast(float, u);
}
__device__ __forceinline__ uint2 packA(float4 v) {
  uint2 r;
  r.x = (unsigned)f2b(v.x) | ((unsigned)f2b(v.y) << 16);
  r.y = (unsigned)f2b(v.z) | ((unsigned)f2b(v.w) << 16);
  return r;
}
__device__ __forceinline__ uint4 packA8(float4 v0, float4 v1) {
  uint4 r;
  r.x = (unsigned)f2b(v0.x) | ((unsigned)f2b(v0.y) << 16);
  r.y = (unsigned)f2b(v0.z) | ((unsigned)f2b(v0.w) << 16);
  r.z = (unsigned)f2b(v1.x) | ((unsigned)f2b(v1.y) << 16);
  r.w = (unsigned)f2b(v1.z) | ((unsigned)f2b(v1.w) << 16);
  return r;
}
__device__ __forceinline__ bf16x8 packA8v(float4 v0, float4 v1) {
  return __builtin_bit_cast(bf16x8, packA8(v0, v1));
}

// ---------------------------------------------------------------------------
// Merged weight conversion: 11 f32->bf16 copies in one launch (z = entry).
// ---------------------------------------------------------------------------
struct CvtAll {
  const float* s[11];
  ushort_t* d[11];
  int n4[11];
};
__global__ void cvt_all_k(CvtAll a) {
  int e = blockIdx.z;
  int i = blockIdx.x * 256 + threadIdx.x;
  if (i >= a.n4[e]) return;
  float4 v = reinterpret_cast<const float4*>(a.s[e])[i];
  ushort4 o;
  o.x = f2b(v.x); o.y = f2b(v.y); o.z = f2b(v.z); o.w = f2b(v.w);
  reinterpret_cast<ushort4*>(a.d[e])[i] = o;
}

// ---------------------------------------------------------------------------
// Shared GRU step descriptor.
// ---------------------------------------------------------------------------
struct GruP {
  const float* h_prev; int hs; int hz;
  const ushort_t* Whh;
  const float* x0f; const ushort_t* x0b; int x0s;
  const ushort_t* W0; int w0ld; int K0;
  const float* x1f; int x1sp; const ushort_t* W1; int w1ld; int K1;
  const float* gxf;
  const ushort_t* gxb; int gxros;
  const float* bih; const float* bhh;
  float* h_out; int os;
  ushort_t* h_out2; int o2s;
};
struct GruP2 { GruP d[2]; };

#define MFMA_ __builtin_amdgcn_mfma_f32_16x16x32_bf16

// ---------------------------------------------------------------------------
// gruL_k: latency-optimized GRU step for rows<=256 launches.
// Tile 32 rows x 16 cols. 256 thr = 4 waves: wr = wv&1 row-half,
// kh = wv>>1 K-half of the unified chunk list. NO LDS staging, NO loop
// barriers: direct global->fragment loads. One end barrier for reduction.
// ---------------------------------------------------------------------------
__device__ __forceinline__ void ldfragL(
    const GruP& p, int ci, int nH, int nX0,
    int arowg, int sl, int colg,
    bf16x8& a, bf16x8& w0, bf16x8& w1, bf16x8& w2, int& isH)
{
  if (ci < nH) {
    int ko = ci * 32 + sl;
    const float* ap = p.h_prev + (size_t)arowg * p.hs + ko;
    a = packA8v(*reinterpret_cast<const float4*>(ap),
                *reinterpret_cast<const float4*>(ap + 4));
    const ushort_t* w = p.Whh + (size_t)colg * 512 + ko;
    w0 = *reinterpret_cast<const bf16x8*>(w);
    w1 = *reinterpret_cast<const bf16x8*>(w + 262144);
    w2 = *reinterpret_cast<const bf16x8*>(w + 524288);
    isH = 1;
  } else if (ci < nH + nX0) {
    int ko = (ci - nH) * 32 + sl;
    if (p.x0b) {
      a = *reinterpret_cast<const bf16x8*>(p.x0b + (size_t)arowg * p.x0s + ko);
    } else {
      const float* ap = p.x0f + (size_t)arowg * p.x0s + ko;
      a = packA8v(*reinterpret_cast<const float4*>(ap),
                  *reinterpret_cast<const float4*>(ap + 4));
    }
    const ushort_t* w = p.W0 + (size_t)colg * p.w0ld + ko;
    w0 = *reinterpret_cast<const bf16x8*>(w);
    w1 = *reinterpret_cast<const bf16x8*>(w + (size_t)512 * p.w0ld);
    w2 = *reinterpret_cast<const bf16x8*>(w + (size_t)1024 * p.w0ld);
    isH = 0;
  } else {
    int ko = (ci - nH - nX0) * 32 + sl;
    const float* ap = p.x1f + (size_t)(arowg & 255) * 12288 + (arowg >> 8) * 384
                      + p.x1sp * 96 + ko;
    a = packA8v(*reinterpret_cast<const float4*>(ap),
                *reinterpret_cast<const float4*>(ap + 4));
    const ushort_t* w = p.W1 + (size_t)colg * p.w1ld + ko;
    w0 = *reinterpret_cast<const bf16x8*>(w);
    w1 = *reinterpret_cast<const bf16x8*>(w + (size_t)512 * p.w1ld);
    w2 = *reinterpret_cast<const bf16x8*>(w + (size_t)1024 * p.w1ld);
    isH = 0;
  }
}

__global__ __launch_bounds__(256) void gruL_k(GruP2 pp)
{
  const GruP p = pp.d[blockIdx.z];
  __shared__ float red[2][64][17];
  const int tid = threadIdx.x;
  const int lane = tid & 63, wv = tid >> 6;
  const int wr = wv & 1, kh = wv >> 1;
  const int r0 = blockIdx.x * 32, c0 = blockIdx.y * 16;
  const int sl = (lane >> 4) * 8;                 // k-slice within chunk
  const int arowg = r0 + wr * 16 + (lane & 15);   // A-frag global row
  const int colg = c0 + (lane & 15);              // B-frag global col (gate 0)
  f32x4 aR = {}, aZ = {}, aNX = {}, aNH = {};

  const int nH = p.hz ? 0 : 16;
  const int nX0 = p.K0 >> 5;
  const int nX1 = p.K1 >> 5;
  const int nc = nH + nX0 + nX1;
  const int nh2 = (nc + 1) >> 1;
  const int base = kh ? nh2 : 0;
  const int myn = kh ? (nc - nh2) : nh2;

  bf16x8 a0, w00, w10, w20; int h0 = 0;
  bf16x8 a1, w01, w11, w21; int h1 = 0;
  if (0 < myn) ldfragL(p, base + 0, nH, nX0, arowg, sl, colg, a0, w00, w10, w20, h0);
  if (1 < myn) ldfragL(p, base + 1, nH, nX0, arowg, sl, colg, a1, w01, w11, w21, h1);

  for (int i = 0; i < myn; i += 2) {
    {
      aR = MFMA_(a0, w00, aR, 0, 0, 0);
      aZ = MFMA_(a0, w10, aZ, 0, 0, 0);
      if (h0) aNH = MFMA_(a0, w20, aNH, 0, 0, 0);
      else    aNX = MFMA_(a0, w20, aNX, 0, 0, 0);
    }
    if (i + 2 < myn) ldfragL(p, base + i + 2, nH, nX0, arowg, sl, colg, a0, w00, w10, w20, h0);
    if (i + 1 < myn) {
      aR = MFMA_(a1, w01, aR, 0, 0, 0);
      aZ = MFMA_(a1, w11, aZ, 0, 0, 0);
      if (h1) aNH = MFMA_(a1, w21, aNH, 0, 0, 0);
      else    aNX = MFMA_(a1, w21, aNX, 0, 0, 0);
    }
    if (i + 3 < myn) ldfragL(p, base + i + 3, nH, nX0, arowg, sl, colg, a1, w01, w11, w21, h1);
  }

  if (kh == 1) {
#pragma unroll
    for (int rg = 0; rg < 4; ++rg) {
      red[wr][lane][rg]      = aR[rg];
      red[wr][lane][4 + rg]  = aZ[rg];
      red[wr][lane][8 + rg]  = aNX[rg];
      red[wr][lane][12 + rg] = aNH[rg];
    }
  }
  __syncthreads();
  if (kh == 0) {
#pragma unroll
    for (int rg = 0; rg < 4; ++rg) {
      int r = r0 + wr * 16 + ((lane >> 4) << 2) + rg;
      int c = c0 + (lane & 15);
      float sr = aR[rg] + red[wr][lane][rg] + p.bhh[c];
      float sz = aZ[rg] + red[wr][lane][4 + rg] + p.bhh[HDIM + c];
      float nx = aNX[rg] + red[wr][lane][8 + rg];
      float nh = aNH[rg] + red[wr][lane][12 + rg] + p.bhh[2 * HDIM + c];
      if (p.bih) { sr += p.bih[c]; sz += p.bih[HDIM + c]; nx += p.bih[2 * HDIM + c]; }
      if (p.gxf) {
        const float* g = p.gxf + (size_t)r * GG;
        sr += g[c]; sz += g[HDIM + c]; nx += g[2 * HDIM + c];
      }
      if (p.gxb) {
        const ushort_t* g = p.gxb + (size_t)(p.gxros + r) * 1536;
        sr += b2f(g[c]); sz += b2f(g[HDIM + c]); nx += b2f(g[2 * HDIM + c]);
      }
      float rgate = 1.f / (1.f + expf(-sr));
      float zgate = 1.f / (1.f + expf(-sz));
      float ngate = tanhf(nx + rgate * nh);
      float hp = p.hz ? 0.f : p.h_prev[(size_t)r * p.hs + c];
      float hv = (1.f - zgate) * ngate + zgate * hp;
      p.h_out[(size_t)r * p.os + c] = hv;
      if (p.h_out2) p.h_out2[(size_t)r * p.o2s + c] = f2b(hv);
    }
  }
}

// ---------------------------------------------------------------------------
// gru_k (R15): 32x32 tile, depth-2 reg prefetch, double-buffered LDS,
// one barrier per chunk. Used for decoder (rows=8192) steps.
// ---------------------------------------------------------------------------
#define LB3(WP, WLD_, G_, KOFF) \
  (*reinterpret_cast<const uint2*>((WP) + (size_t)((G_) * HDIM + c0 + bn) * (size_t)(WLD_) + (KOFF) + bk))

#define AL_H(KOFF, DST)  DST = packA(*reinterpret_cast<const float4*>(p.h_prev + (size_t)(r0 + arow) * p.hs + (KOFF) + ak));
#define AL_X0F(KOFF, DST) DST = packA(*reinterpret_cast<const float4*>(p.x0f + (size_t)(r0 + arow) * p.x0s + (KOFF) + ak));
#define AL_X0B(KOFF, DST) DST = *reinterpret_cast<const uint2*>(p.x0b + (size_t)(r0 + arow) * p.x0s + (KOFF) + ak);
#define AL_CH(KOFF, DST) { int rr_ = r0 + arow; \
  DST = packA(*reinterpret_cast<const float4*>(p.x1f + (size_t)(rr_ & 255) * 12288 + (rr_ >> 8) * 384 + p.x1sp * 96 + (KOFF) + ak)); }

#define GRU_MMA(B_, ACCN)                                                      \
  { bf16x8 afr = *reinterpret_cast<const bf16x8*>(&Xs[B_][wr * 16 + (lane & 15)][(lane >> 4) * 8]); \
    bf16x8 f0 = *reinterpret_cast<const bf16x8*>(&Bs[B_][0][wc * 16 + (lane & 15)][(lane >> 4) * 8]); \
    bf16x8 f1 = *reinterpret_cast<const bf16x8*>(&Bs[B_][1][wc * 16 + (lane & 15)][(lane >> 4) * 8]); \
    bf16x8 f2 = *reinterpret_cast<const bf16x8*>(&Bs[B_][2][wc * 16 + (lane & 15)][(lane >> 4) * 8]); \
    aR = MFMA_(afr, f0, aR, 0, 0, 0);                                          \
    aZ = MFMA_(afr, f1, aZ, 0, 0, 0);                                          \
    ACCN = MFMA_(afr, f2, ACCN, 0, 0, 0); }

#define GRU_PHASE(KLEN, ALOAD, WP, WLD_, ACCN)                                 \
  { uint2 aP0, aP1;                                                            \
    uint2 b0P0, b1P0, b2P0, b0P1, b1P1, b2P1;                                  \
    ALOAD(0, aP0)                                                              \
    b0P0 = LB3(WP, WLD_, 0, 0); b1P0 = LB3(WP, WLD_, 1, 0); b2P0 = LB3(WP, WLD_, 2, 0); \
    if ((KLEN) > 32) {                                                         \
      ALOAD(32, aP1)                                                           \
      b0P1 = LB3(WP, WLD_, 0, 32); b1P1 = LB3(WP, WLD_, 1, 32); b2P1 = LB3(WP, WLD_, 2, 32); \
    }                                                                          \
    __syncthreads();                                                           \
    for (int k0 = 0; k0 < (KLEN); k0 += 64) {                                  \
      *reinterpret_cast<uint2*>(&Xs[0][arow][ak]) = aP0;                       \
      *reinterpret_cast<uint2*>(&Bs[0][0][bn][bk]) = b0P0;                     \
      *reinterpret_cast<uint2*>(&Bs[0][1][bn][bk]) = b1P0;                     \
      *reinterpret_cast<uint2*>(&Bs[0][2][bn][bk]) = b2P0;                     \
      if (k0 + 64 < (KLEN)) {                                                  \
        ALOAD(k0 + 64, aP0)                                                    \
        b0P0 = LB3(WP, WLD_, 0, k0 + 64); b1P0 = LB3(WP, WLD_, 1, k0 + 64); b2P0 = LB3(WP, WLD_, 2, k0 + 64); \
      }                                                                        \
      __syncthreads();                                                         \
      GRU_MMA(0, ACCN)                                                         \
      if (k0 + 32 < (KLEN)) {                                                  \
        *reinterpret_cast<uint2*>(&Xs[1][arow][ak]) = aP1;                     \
        *reinterpret_cast<uint2*>(&Bs[1][0][bn][bk]) = b0P1;                   \
        *reinterpret_cast<uint2*>(&Bs[1][1][bn][bk]) = b1P1;                   \
        *reinterpret_cast<uint2*>(&Bs[1][2][bn][bk]) = b2P1;                   \
        if (k0 + 96 < (KLEN)) {                                                \
          ALOAD(k0 + 96, aP1)                                                  \
          b0P1 = LB3(WP, WLD_, 0, k0 + 96); b1P1 = LB3(WP, WLD_, 1, k0 + 96); b2P1 = LB3(WP, WLD_, 2, k0 + 96); \
        }                                                                      \
        __syncthreads();                                                       \
        GRU_MMA(1, ACCN)                                                       \
      }                                                                        \
    } }

__global__ __launch_bounds__(256) void gru_k(GruP2 pp)
{
  const GruP p = pp.d[blockIdx.z];
  __shared__ ushort_t Xs[2][32][40];
  __shared__ ushort_t Bs[2][3][32][40];
  const int tid = threadIdx.x;
  const int lane = tid & 63, wv = tid >> 6;
  const int wr = wv >> 1, wc = wv & 1;
  const int r0 = blockIdx.x * 32, c0 = blockIdx.y * 32;
  const int arow = tid >> 3, ak = (tid & 7) * 4;
  const int bn = tid >> 3, bk = (tid & 7) * 4;
  f32x4 aR = {}, aZ = {}, aNX = {}, aNH = {};

  if (!p.hz) { GRU_PHASE(HDIM, AL_H, p.Whh, HDIM, aNH) }
  if (p.K0 > 0) {
    if (p.x0b) { GRU_PHASE(p.K0, AL_X0B, p.W0, p.w0ld, aNX) }
    else       { GRU_PHASE(p.K0, AL_X0F, p.W0, p.w0ld, aNX) }
  }
  if (p.K1 > 0) { GRU_PHASE(p.K1, AL_CH, p.W1, p.w1ld, aNX) }

#pragma unroll
  for (int rg = 0; rg < 4; ++rg) {
    int r = r0 + wr * 16 + ((lane >> 4) << 2) + rg;
    int c = c0 + wc * 16 + (lane & 15);
    float sr = aR[rg] + p.bhh[c];
    float sz = aZ[rg] + p.bhh[HDIM + c];
    float nx = aNX[rg];
    float nh = aNH[rg] + p.bhh[2 * HDIM + c];
    if (p.bih) { sr += p.bih[c]; sz += p.bih[HDIM + c]; nx += p.bih[2 * HDIM + c]; }
    if (p.gxf) {
      const float* g = p.gxf + (size_t)r * GG;
      sr += g[c]; sz += g[HDIM + c]; nx += g[2 * HDIM + c];
    }
    if (p.gxb) {
      const ushort_t* g = p.gxb + (size_t)(p.gxros + r) * 1536;
      sr += b2f(g[c]); sz += b2f(g[HDIM + c]); nx += b2f(g[2 * HDIM + c]);
    }
    float rgate = 1.f / (1.f + expf(-sr));
    float zgate = 1.f / (1.f + expf(-sz));
    float ngate = tanhf(nx + rgate * nh);
    float hp = p.hz ? 0.f : p.h_prev[(size_t)r * p.hs + c];
    float hv = (1.f - zgate) * ngate + zgate * hp;
    p.h_out[(size_t)r * p.os + c] = hv;
    if (p.h_out2) p.h_out2[(size_t)r * p.o2s + c] = f2b(hv);
  }
}

// ---------------------------------------------------------------------------
// gx GEMM for enc1: C_bf16[2][4096][1536] = y0b @ W^T + bias. Both dirs in
// one launch (dir = rBase>>12). Tile 64x128, 512 thr.
// ---------------------------------------------------------------------------
__global__ __launch_bounds__(512) void gx_gemm_k(
    const ushort_t* __restrict__ Aarg, const ushort_t* __restrict__ W,
    int ldw, int dirWStride,
    const float* __restrict__ bias, ushort_t* __restrict__ C, int t0, int K)
{
  __shared__ ushort_t As[64][40];
  __shared__ ushort_t Bs[128][40];
  const int tid = threadIdx.x;
  const int lane = tid & 63, wv = tid >> 6;
  const int wr = wv >> 2, wc = wv & 3;
  const int rBase = blockIdx.x * 64, n0 = blockIdx.y * 128;
  const int dir = rBase >> 12;
  const int arow = tid >> 3, ak = (tid & 7) * 4;
  const int bcol = tid >> 2, bk = (tid & 3) * 8;
  int r = rBase + arow;
  int tl = (r >> 8) & 15, b = r & 255;
  int tsrc = (dir == 0) ? (t0 + tl) : (127 - t0 - tl);
  const ushort_t* apB = Aarg + (size_t)b * 131072 + (size_t)tsrc * 1024;
  const ushort_t* wrow = W + (size_t)dir * dirWStride + (size_t)(n0 + bcol) * ldw;
  f32x4 acc[2][2] = {};

  uint2 aC = *reinterpret_cast<const uint2*>(apB + ak);
  uint4 bC = *reinterpret_cast<const uint4*>(wrow + bk);
  for (int k0 = 0; k0 < K; k0 += 32) {
    __syncthreads();
    *reinterpret_cast<uint2*>(&As[arow][ak]) = aC;
    *reinterpret_cast<uint4*>(&Bs[bcol][bk]) = bC;
    if (k0 + 32 < K) {
      aC = *reinterpret_cast<const uint2*>(apB + k0 + 32 + ak);
      bC = *reinterpret_cast<const uint4*>(wrow + k0 + 32 + bk);
    }
    __syncthreads();
    bf16x8 af[2], bf[2];
#pragma unroll
    for (int i = 0; i < 2; ++i)
      af[i] = *reinterpret_cast<const bf16x8*>(&As[wr * 32 + i * 16 + (lane & 15)][(lane >> 4) * 8]);
#pragma unroll
    for (int j = 0; j < 2; ++j)
      bf[j] = *reinterpret_cast<const bf16x8*>(&Bs[wc * 32 + j * 16 + (lane & 15)][(lane >> 4) * 8]);
#pragma unroll
    for (int i = 0; i < 2; ++i)
#pragma unroll
      for (int j = 0; j < 2; ++j)
        acc[i][j] = __builtin_amdgcn_mfma_f32_16x16x32_bf16(af[i], bf[j], acc[i][j], 0, 0, 0);
  }
#pragma unroll
  for (int i = 0; i < 2; ++i)
#pragma unroll
    for (int j = 0; j < 2; ++j)
#pragma unroll
      for (int rg = 0; rg < 4; ++rg) {
        int rr = rBase + wr * 32 + i * 16 + ((lane >> 4) << 2) + rg;
        int cc = n0 + wc * 32 + j * 16 + (lane & 15);
        C[(size_t)rr * 1536 + cc] = f2b(acc[i][j][rg] + bias[dir * 1536 + cc]);
      }
}

// ---------------------------------------------------------------------------
// Decoder emb GEMM: C_bf16[8192][1536] = h1c @ dec0_Wih[:, :512]^T + bih.
// ---------------------------------------------------------------------------
__global__ __launch_bounds__(256) void gemm_demb_k(
    const float* __restrict__ A,
    const ushort_t* __restrict__ W, int ldw,
    const float* __restrict__ bias,
    ushort_t* __restrict__ C)
{
  __shared__ ushort_t As[32][40];
  __shared__ ushort_t Bs[64][40];
  const int tid = threadIdx.x;
  const int lane = tid & 63, wv = tid >> 6;
  const int wr = wv >> 1, wc = wv & 1;
  const int r0 = blockIdx.x * 32, c0 = blockIdx.y * 64;
  const int arow = tid >> 3, ak = (tid & 7) * 4;
  const int bn = tid >> 2, bk = (tid & 3) * 8;
  f32x4 acc[2] = {};
  const float* arowp = A + (size_t)(r0 + arow) * 512;
  const ushort_t* wrow = W + (size_t)(c0 + bn) * ldw;

  uint2 aC = packA(*reinterpret_cast<const float4*>(arowp + ak));
  uint4 bC = *reinterpret_cast<const uint4*>(wrow + bk);
  for (int k0 = 0; k0 < 512; k0 += 32) {
    __syncthreads();
    *reinterpret_cast<uint2*>(&As[arow][ak]) = aC;
    *reinterpret_cast<uint4*>(&Bs[bn][bk]) = bC;
    if (k0 + 32 < 512) {
      aC = packA(*reinterpret_cast<const float4*>(arowp + k0 + 32 + ak));
      bC = *reinterpret_cast<const uint4*>(wrow + k0 + 32 + bk);
    }
    __syncthreads();
    bf16x8 afr = *reinterpret_cast<const bf16x8*>(&As[wr * 16 + (lane & 15)][(lane >> 4) * 8]);
#pragma unroll
    for (int j = 0; j < 2; ++j) {
      bf16x8 bfr = *reinterpret_cast<const bf16x8*>(&Bs[wc * 32 + j * 16 + (lane & 15)][(lane >> 4) * 8]);
      acc[j] = __builtin_amdgcn_mfma_f32_16x16x32_bf16(afr, bfr, acc[j], 0, 0, 0);
    }
  }
#pragma unroll
  for (int j = 0; j < 2; ++j)
#pragma unroll
    for (int rg = 0; rg < 4; ++rg) {
      int r = r0 + wr * 16 + ((lane >> 4) << 2) + rg;
      int c = c0 + wc * 32 + j * 16 + (lane & 15);
      C[(size_t)r * 1536 + c] = f2b(acc[j][rg] + bias[c]);
    }
}

// ---------------------------------------------------------------------------
// Generic MFMA GEMM (f32 A, f32 W cvt on the fly), 32x64 tile.
// ---------------------------------------------------------------------------
__global__ __launch_bounds__(256) void mfma_gemm_k(
    const float* __restrict__ A, int lda,
    const float* __restrict__ W, int ldw,
    const float* __restrict__ bias,
    float* __restrict__ C, int ldc, int N, int K)
{
  __shared__ ushort_t As[32][40];
  __shared__ ushort_t Bs[64][40];
  const int tid = threadIdx.x;
  const int lane = tid & 63, wv = tid >> 6;
  const int wr = wv >> 1, wc = wv & 1;
  const int r0 = blockIdx.x * 32, c0 = blockIdx.y * 64;
  const int arow = tid >> 3, ak = (tid & 7) * 4;
  const int bn = tid >> 2, bk = (tid & 3) * 8;
  f32x4 acc[2] = {};
  const int nOk = (c0 + bn) < N;
  const float* wrow = W + (size_t)(nOk ? (c0 + bn) : 0) * ldw;

  uint2 aC = packA(*reinterpret_cast<const float4*>(A + (size_t)(r0 + arow) * lda + ak));
  uint4 bC;
  {
    float4 v0 = *reinterpret_cast<const float4*>(wrow + bk);
    float4 v1 = *reinterpret_cast<const float4*>(wrow + bk + 4);
    bC = packA8(v0, v1);
  }
  for (int k0 = 0; k0 < K; k0 += 32) {
    __syncthreads();
    *reinterpret_cast<uint2*>(&As[arow][ak]) = aC;
    if (nOk) *reinterpret_cast<uint4*>(&Bs[bn][bk]) = bC;
    else { uint4 z; z.x = z.y = z.z = z.w = 0; *reinterpret_cast<uint4*>(&Bs[bn][bk]) = z; }
    if (k0 + 32 < K) {
      aC = packA(*reinterpret_cast<const float4*>(A + (size_t)(r0 + arow) * lda + k0 + 32 + ak));
      float4 v0 = *reinterpret_cast<const float4*>(wrow + k0 + 32 + bk);
      float4 v1 = *reinterpret_cast<const float4*>(wrow + k0 + 32 + bk + 4);
      bC = packA8(v0, v1);
    }
    __syncthreads();
    bf16x8 afr = *reinterpret_cast<const bf16x8*>(&As[wr * 16 + (lane & 15)][(lane >> 4) * 8]);
#pragma unroll
    for (int j = 0; j < 2; ++j) {
      bf16x8 bfr = *reinterpret_cast<const bf16x8*>(&Bs[wc * 32 + j * 16 + (lane & 15)][(lane >> 4) * 8]);
      acc[j] = __builtin_amdgcn_mfma_f32_16x16x32_bf16(afr, bfr, acc[j], 0, 0, 0);
    }
  }
#pragma unroll
  for (int j = 0; j < 2; ++j)
#pragma unroll
    for (int rg = 0; rg < 4; ++rg) {
      int r = r0 + wr * 16 + ((lane >> 4) << 2) + rg;
      int c = c0 + wc * 32 + j * 16 + (lane & 15);
      if (c < N) C[(size_t)r * ldc + c] = acc[j][rg] + (bias ? bias[c] : 0.f);
    }
}

// ---------------------------------------------------------------------------
// Small elementwise kernels
// ---------------------------------------------------------------------------
__global__ void gather_hidden_k(const ushort_t* __restrict__ y0b,
                                const float* __restrict__ h1f,
                                const float* __restrict__ h1b,
                                float* __restrict__ hidden)
{
  int i = blockIdx.x * 256 + threadIdx.x;
  if (i >= BB * 4 * HDIM) return;
  int b = i >> 11, j = i & 2047;
  float v;
  if (j < 512)       v = b2f(y0b[(size_t)b * 131072 + 127 * 1024 + j]);
  else if (j < 1024) v = b2f(y0b[(size_t)b * 131072 + j]);
  else if (j < 1536) v = h1f[b * 512 + (j - 1024)];
  else               v = h1b[b * 512 + (j - 1536)];
  hidden[i] = v;
}

__global__ void z_k(const float* __restrict__ mu, const float* __restrict__ lv,
                    const float* __restrict__ eps, float* __restrict__ z,
                    float* __restrict__ out_mu, float* __restrict__ out_lv)
{
  int i = blockIdx.x * 256 + threadIdx.x;
  if (i >= BB * HDIM) return;
  float m = mu[i], l = lv[i];
  z[i] = eps[i] * expf(0.5f * l) + m;
  out_mu[i] = m;
  out_lv[i] = l;
}

__global__ void softmax_k(const float* __restrict__ logits,
                          float* __restrict__ out_sm,
                          float* __restrict__ out_lsm)
{
  int q = blockIdx.x;
  int lane = threadIdx.x;
  const float* row = logits + (size_t)q * 96;
  float v0 = row[lane];
  float v1 = (lane < 32) ? row[lane + 64] : -1e30f;
  float m = fmaxf(v0, v1);
#pragma unroll
  for (int o = 32; o; o >>= 1) m = fmaxf(m, __shfl_xor(m, o));
  float e0 = expf(v0 - m);
  float e1 = (lane < 32) ? expf(v1 - m) : 0.f;
  float s = e0 + e1;
#pragma unroll
  for (int o = 32; o; o >>= 1) s += __shfl_xor(s, o);
  float inv = 1.f / s, ls = logf(s);
  int b = (q >> 2) & 255;
  int t = (q >> 10) * 4 + (q & 3);
  size_t base = (size_t)b * TT * 96 + (size_t)t * 96;
  out_sm[base + lane]  = e0 * inv;
  out_lsm[base + lane] = v0 - m - ls;
  if (lane < 32) {
    out_sm[base + lane + 64]  = e1 * inv;
    out_lsm[base + lane + 64] = v1 - m - ls;
  }
}

__global__ void echo_k(const float* __restrict__ in, float* __restrict__ out)
{
  int i = blockIdx.x * 256 + threadIdx.x;
  if (i < BB * TT * NCC) out[i] = in[i];
}

// ---------------------------------------------------------------------------
extern "C" void kernel_launch(void* const* d_in, const int* in_sizes, int n_in,
                              void* d_out, int out_size, void* d_ws, size_t ws_size,
                              hipStream_t stream)
{
  const float* in        = (const float*)d_in[0];
  const float* eps       = (const float*)d_in[2];
  const float* enc0_Wih  = (const float*)d_in[3];
  const float* enc0_Whh  = (const float*)d_in[4];
  const float* enc0_bih  = (const float*)d_in[5];
  const float* enc0_bhh  = (const float*)d_in[6];
  const float* enc1_Wih  = (const float*)d_in[7];
  const float* enc1_Whh  = (const float*)d_in[8];
  const float* enc1_bih  = (const float*)d_in[9];
  const float* enc1_bhh  = (const float*)d_in[10];
  const float* con0_Wih  = (const float*)d_in[11];
  const float* con0_Whh  = (const float*)d_in[12];
  const float* con0_bih  = (const float*)d_in[13];
  const float* con0_bhh  = (const float*)d_in[14];
  const float* con1_Wih  = (const float*)d_in[15];
  const float* con1_Whh  = (const float*)d_in[16];
  const float* con1_bih  = (const float*)d_in[17];
  const float* con1_bhh  = (const float*)d_in[18];
  const float* dec0_Wih  = (const float*)d_in[19];
  const float* dec0_Whh  = (const float*)d_in[20];
  const float* dec0_bih  = (const float*)d_in[21];
  const float* dec0_bhh  = (const float*)d_in[22];
  const float* dec1_Wih  = (const float*)d_in[23];
  const float* dec1_Whh  = (const float*)d_in[24];
  const float* dec1_bih  = (const float*)d_in[25];
  const float* dec1_bhh  = (const float*)d_in[26];
  const float* W_mu      = (const float*)d_in[27];
  const float* b_mu      = (const float*)d_in[28];
  const float* W_lv      = (const float*)d_in[29];
  const float* b_lv      = (const float*)d_in[30];
  const float* W_ci      = (const float*)d_in[31];
  const float* b_ci      = (const float*)d_in[32];
  const float* W_ch      = (const float*)d_in[33];
  const float* b_ch      = (const float*)d_in[34];
  const float* W_out     = (const float*)d_in[35];
  const float* b_out     = (const float*)d_in[36];

  // ---- workspace layout (f32 slots; 33,554,432 = 128 MiB exactly) ----------
  float* ws = (float*)d_ws;
  ushort_t* y0b  = (ushort_t*)ws;                      // [256][128][1024] bf16
  float* e0pp    = ws + 16777216;                      // [2pp][2dir][256][512]
  ushort_t* gxAll = (ushort_t*)(ws + 17301504);        // [2][4096][1536] bf16
  // decoder-phase aliases (y0b/e0pp/gxAll dead):
  float* h0c   = ws;                                   // [32][256][512]
  float* h1c   = ws + 4194304;
  float* d0p[2] = { ws + 8388608,  ws + 12582912 };
  float* d1p[2] = { ws + 16777216, ws + 20971520 };
  // persistent smalls
  float* mu_f  = ws + 26492928;
  float* lv_f  = ws + 26624000;
  float* zz    = ws + 26755072;
  float* ci    = ws + 26886144;
  float* chv   = ws + 26910720;
  float* gx_c0 = ws + 27041792;
  ushort_t* Wb = (ushort_t*)(ws + 27435008);           // 12,238,848 bf16

  ushort_t* wb_e0_Wih = Wb;
  ushort_t* wb_e0_Whh = Wb + 294912;
  ushort_t* wb_e1_Wih = Wb + 1867776;
  ushort_t* wb_e1_Whh = Wb + 5013504;
  ushort_t* wb_c0_Whh = Wb + 6586368;
  ushort_t* wb_c1_Wih = Wb + 7372800;
  ushort_t* wb_c1_Whh = Wb + 8159232;
  ushort_t* wb_d0_Wih = Wb + 8945664;
  ushort_t* wb_d0_Whh = Wb + 9879552;
  ushort_t* wb_d1_Wih = Wb + 10665984;
  ushort_t* wb_d1_Whh = Wb + 11452416;

  float* outp   = (float*)d_out;
  float* out_sm = outp;
  float* out_ls = outp + 3145728;
  float* out_mu = outp + 6291456;
  float* out_lv = outp + 6422528;
  float* out_ec = outp + 6553600;
  // gx_demb scratch occupies out_sm+out_ls regions, dead before softmax_k.
  ushort_t* gx_demb = (ushort_t*)outp;
  // scratch in echo region (dead before echo_k)
  float* fscr = out_ec;
  float* h1f_pp[2] = { fscr,          fscr + 131072 };
  float* h1b_pp[2] = { fscr + 262144, fscr + 393216 };
  float* hidden    = fscr + 524288;                    // [256][2048]
  float* logits_q  = out_ec;                           // decoder: [8192 x 384]

  auto gemmM = [&](const float* A, int lda, const float* W, int ldw, const float* bias,
                   float* C, int ldc, int M, int N, int K) {
    mfma_gemm_k<<<dim3(M / 32, (N + 63) / 64), 256, 0, stream>>>(A, lda, W, ldw, bias, C, ldc, N, K);
  };
  // latency-optimized step (rows = 256): barrier-free direct-load kernel
  auto gruL2 = [&](const GruP& a, const GruP& b) {
    GruP2 q; q.d[0] = a; q.d[1] = b;
    gruL_k<<<dim3(8, 32, 2), 256, 0, stream>>>(q);
  };
  auto gruL1 = [&](const GruP& a) {
    GruP2 q; q.d[0] = a; q.d[1] = a;
    gruL_k<<<dim3(8, 32, 1), 256, 0, stream>>>(q);
  };
  // throughput step (decoder rows = 8192)
  auto gru1 = [&](const GruP& a, int rows) {
    GruP2 q; q.d[0] = a; q.d[1] = a;
    gru_k<<<dim3(rows / 32, 16, 1), 256, 0, stream>>>(q);
  };

  // ---------------- weight conversion (single launch) ------------------------
  {
    CvtAll ca;
    const float* srcs[11] = { enc0_Wih, enc0_Whh, enc1_Wih, enc1_Whh, con0_Whh,
                              con1_Wih, con1_Whh, dec0_Wih, dec0_Whh, dec1_Wih, dec1_Whh };
    ushort_t* dsts[11] = { wb_e0_Wih, wb_e0_Whh, wb_e1_Wih, wb_e1_Whh, wb_c0_Whh,
                           wb_c1_Wih, wb_c1_Whh, wb_d0_Wih, wb_d0_Whh, wb_d1_Wih, wb_d1_Whh };
    int ns[11] = { 294912, 1572864, 3145728, 1572864, 786432,
                   786432, 786432, 933888, 786432, 786432, 786432 };
    for (int e = 0; e < 11; ++e) { ca.s[e] = srcs[e]; ca.d[e] = dsts[e]; ca.n4[e] = ns[e] / 4; }
    cvt_all_k<<<dim3(3072, 1, 11), 256, 0, stream>>>(ca);
  }

  // ---------------- encoder layer 0 (per-step, inline x) ---------------------
  for (int t = 0; t < TT; ++t) {
    int tr = TT - 1 - t;
    GruP f = {};
    f.hz = (t == 0);
    f.h_prev = e0pp + (size_t)((t + 1) & 1) * 262144; f.hs = 512;
    f.x0f = in + (size_t)t * 96; f.x0s = 12288; f.W0 = wb_e0_Wih; f.w0ld = 96; f.K0 = 96;
    f.Whh = wb_e0_Whh; f.bih = enc0_bih; f.bhh = enc0_bhh;
    f.h_out = e0pp + (size_t)(t & 1) * 262144; f.os = 512;
    f.h_out2 = y0b + (size_t)t * 1024; f.o2s = 131072;
    GruP bd = {};
    bd.hz = (t == 0);
    bd.h_prev = e0pp + (size_t)((t + 1) & 1) * 262144 + 131072; bd.hs = 512;
    bd.x0f = in + (size_t)tr * 96; bd.x0s = 12288;
    bd.W0 = wb_e0_Wih + 147456; bd.w0ld = 96; bd.K0 = 96;
    bd.Whh = wb_e0_Whh + 786432; bd.bih = enc0_bih + GG; bd.bhh = enc0_bhh + GG;
    bd.h_out = e0pp + (size_t)(t & 1) * 262144 + 131072; bd.os = 512;
    bd.h_out2 = y0b + (size_t)tr * 1024 + 512; bd.o2s = 131072;
    gruL2(f, bd);
  }

  // ---------------- encoder layer 1 (fused-dir gx + per-step) ----------------
  for (int ch = 0; ch < 8; ++ch) {
    int t0 = ch * 16;
    gx_gemm_k<<<dim3(128, 12), 512, 0, stream>>>(
        y0b, wb_e1_Wih, 1024, 1572864, enc1_bih, gxAll, t0, 1024);
    for (int tl = 0; tl < 16; ++tl) {
      int t = t0 + tl;
      GruP f = {};
      f.hz = (t == 0);
      f.h_prev = h1f_pp[(t + 1) & 1]; f.hs = 512;
      f.Whh = wb_e1_Whh; f.bhh = enc1_bhh;
      f.gxb = gxAll; f.gxros = tl * 256;
      f.h_out = h1f_pp[t & 1]; f.os = 512;
      GruP bd = {};
      bd.hz = (t == 0);
      bd.h_prev = h1b_pp[(t + 1) & 1]; bd.hs = 512;
      bd.Whh = wb_e1_Whh + 786432; bd.bhh = enc1_bhh + GG;
      bd.gxb = gxAll + 6291456; bd.gxros = tl * 256;
      bd.h_out = h1b_pp[t & 1]; bd.os = 512;
      gruL2(f, bd);
    }
  }

  // ---------------- latent ----------------------------------------------------
  gather_hidden_k<<<2048, 256, 0, stream>>>(y0b, h1f_pp[1], h1b_pp[1], hidden);
  gemmM(hidden, 2048, W_mu, 2048, b_mu, mu_f, 512, BB, 512, 2048);
  gemmM(hidden, 2048, W_lv, 2048, b_lv, lv_f, 512, BB, 512, 2048);
  z_k<<<512, 256, 0, stream>>>(mu_f, lv_f, eps, zz, out_mu, out_lv);
  gemmM(zz, 512, W_ci, 512, b_ci, ci, 96, BB, 96, 512);
  gemmM(zz, 512, W_ch, 512, b_ch, chv, 512, BB, 512, 512);
  gemmM(ci, 96, con0_Wih, 96, con0_bih, gx_c0, GG, BB, GG, 96);

  // ---------------- conductor (fused: 33 launches) ---------------------------
  auto c0desc = [&](int bar) {
    GruP c0 = {};
    c0.h_prev = (bar == 0) ? chv : h0c + (size_t)(bar - 1) * 131072; c0.hs = 512;
    c0.gxf = gx_c0;
    c0.Whh = wb_c0_Whh; c0.bhh = con0_bhh;
    c0.h_out = h0c + (size_t)bar * 131072; c0.os = 512;
    return c0;
  };
  auto c1desc = [&](int bar) {
    GruP c1 = {};
    c1.h_prev = (bar == 0) ? chv : h1c + (size_t)(bar - 1) * 131072; c1.hs = 512;
    c1.x0f = h0c + (size_t)bar * 131072; c1.x0s = 512;
    c1.W0 = wb_c1_Wih; c1.w0ld = 512; c1.K0 = 512;
    c1.Whh = wb_c1_Whh; c1.bih = con1_bih; c1.bhh = con1_bhh;
    c1.h_out = h1c + (size_t)bar * 131072; c1.os = 512;
    return c1;
  };
  gruL1(c0desc(0));
  for (int bar = 1; bar < NBB; ++bar) gruL2(c0desc(bar), c1desc(bar - 1));
  gruL1(c1desc(NBB - 1));

  // ---------------- decoder: emb-proj hoisted, 8192 rows, 4 steps ------------
  gemm_demb_k<<<dim3(256, 24), 256, 0, stream>>>(h1c, wb_d0_Wih, 608, dec0_bih, gx_demb);
  const int R = NBB * BB;
  for (int s = 0; s < CPBB; ++s) {
    GruP d0 = {};
    d0.h_prev = (s == 0) ? h0c : d0p[(s - 1) & 1]; d0.hs = 512;
    d0.x1f = in; d0.x1sp = s; d0.W1 = wb_d0_Wih + 512; d0.w1ld = 608; d0.K1 = 96;
    d0.gxb = gx_demb; d0.gxros = 0;
    d0.Whh = wb_d0_Whh; d0.bhh = dec0_bhh;
    d0.h_out = d0p[s & 1]; d0.os = 512;
    gru1(d0, R);
    GruP d1 = {};
    d1.h_prev = (s == 0) ? h1c : d1p[(s - 1) & 1]; d1.hs = 512;
    d1.x0f = d0p[s & 1]; d1.x0s = 512; d1.W0 = wb_d1_Wih; d1.w0ld = 512; d1.K0 = 512;
    d1.Whh = wb_d1_Whh; d1.bih = dec1_bih; d1.bhh = dec1_bhh;
    d1.h_out = d1p[s & 1]; d1.os = 512;
    gru1(d1, R);
    gemmM(d1p[s & 1], 512, W_out, 512, b_out, logits_q + (size_t)s * 96, 384, R, 96, 512);
  }

  // ---------------- softmax + echo --------------------------------------------
  softmax_k<<<NBB * BB * CPBB, 64, 0, stream>>>(logits_q, out_sm, out_ls);
  echo_k<<<12288, 256, 0, stream>>>(in, out_ec);
}

// Round 17
// 4216.937 us; speedup vs baseline: 1.3540x; 1.3540x over previous
//
#include <hip/hip_runtime.h>

// MusicVAE forward. B=256, T=128, NC=96, H=512, G=1536, NB=32, CPB=4.
// All inputs f32; all outputs f32. bf16 MFMA compute, f32 state/accumulate.
// R13 structure (best: 4294us): gru_k 32x32 tile, 4 waves, depth-2 reg
// prefetch. Decoder d0(s) fused with d1(s-1) via z=2 (launch reduction).

#define BB   256
#define TT   128
#define NCC  96
#define HDIM 512
#define GG   1536
#define NBB  32
#define CPBB 4

typedef __attribute__((ext_vector_type(4))) float f32x4;
typedef __attribute__((ext_vector_type(8))) short bf16x8;
typedef unsigned short ushort_t;

__device__ __forceinline__ unsigned short f2b(float x) {
  unsigned int u = __builtin_bit_cast(unsigned int, x);
  u += 0x7fff + ((u >> 16) & 1);
  return (unsigned short)(u >> 16);
}
__device__ __forceinline__ float b2f(unsigned short h) {
  unsigned int u = ((unsigned int)h) << 16;
  return __builtin_bit_cast(float, u);
}
__device__ __forceinline__ uint2 packA(float4 v) {
  uint2 r;
  r.x = (unsigned)f2b(v.x) | ((unsigned)f2b(v.y) << 16);
  r.y = (unsigned)f2b(v.z) | ((unsigned)f2b(v.w) << 16);
  return r;
}
__device__ __forceinline__ uint4 packA8(float4 v0, float4 v1) {
  uint4 r;
  r.x = (unsigned)f2b(v0.x) | ((unsigned)f2b(v0.y) << 16);
  r.y = (unsigned)f2b(v0.z) | ((unsigned)f2b(v0.w) << 16);
  r.z = (unsigned)f2b(v1.x) | ((unsigned)f2b(v1.y) << 16);
  r.w = (unsigned)f2b(v1.z) | ((unsigned)f2b(v1.w) << 16);
  return r;
}

// ---------------------------------------------------------------------------
// Merged weight conversion: 11 f32->bf16 copies in one launch (z = entry).
// ---------------------------------------------------------------------------
struct CvtAll {
  const float* s[11];
  ushort_t* d[11];
  int n4[11];
};
__global__ void cvt_all_k(CvtAll a) {
  int e = blockIdx.z;
  int i = blockIdx.x * 256 + threadIdx.x;
  if (i >= a.n4[e]) return;
  float4 v = reinterpret_cast<const float4*>(a.s[e])[i];
  ushort4 o;
  o.x = f2b(v.x); o.y = f2b(v.y); o.z = f2b(v.z); o.w = f2b(v.w);
  reinterpret_cast<ushort4*>(a.d[e])[i] = o;
}

// ---------------------------------------------------------------------------
// GRU step. Tile 32 rows x 32 cols, 4 waves (2x2 of 16x16), BK=32 chunks,
// DEPTH-2 register pipeline, grid fills all 256 CUs per step. (R13-proven)
// ---------------------------------------------------------------------------
struct GruP {
  const float* h_prev; int hs; int hz;
  const ushort_t* Whh;
  const float* x0f; const ushort_t* x0b; int x0s;
  const ushort_t* W0; int w0ld; int K0;
  const float* x1f; int x1sp; const ushort_t* W1; int w1ld; int K1;
  const float* gxf;
  const ushort_t* gxb; int gxros;
  const float* bih; const float* bhh;
  float* h_out; int os;
  ushort_t* h_out2; int o2s;
};
struct GruP2 { GruP d[2]; };

#define LB3(WP, WLD_, G_, KOFF) \
  (*reinterpret_cast<const uint2*>((WP) + (size_t)((G_) * HDIM + c0 + bn) * (size_t)(WLD_) + (KOFF) + bk))

#define AL_H(KOFF, DST)  DST = packA(*reinterpret_cast<const float4*>(p.h_prev + (size_t)(r0 + arow) * p.hs + (KOFF) + ak));
#define AL_X0F(KOFF, DST) DST = packA(*reinterpret_cast<const float4*>(p.x0f + (size_t)(r0 + arow) * p.x0s + (KOFF) + ak));
#define AL_X0B(KOFF, DST) DST = *reinterpret_cast<const uint2*>(p.x0b + (size_t)(r0 + arow) * p.x0s + (KOFF) + ak);
#define AL_CH(KOFF, DST) { int rr_ = r0 + arow; \
  DST = packA(*reinterpret_cast<const float4*>(p.x1f + (size_t)(rr_ & 255) * 12288 + (rr_ >> 8) * 384 + p.x1sp * 96 + (KOFF) + ak)); }

#define GRU_MMA(ACCN)                                                          \
  { bf16x8 afr = *reinterpret_cast<const bf16x8*>(&Xs[wr * 16 + (lane & 15)][(lane >> 4) * 8]); \
    bf16x8 f0 = *reinterpret_cast<const bf16x8*>(&Bs[0][wc * 16 + (lane & 15)][(lane >> 4) * 8]); \
    bf16x8 f1 = *reinterpret_cast<const bf16x8*>(&Bs[1][wc * 16 + (lane & 15)][(lane >> 4) * 8]); \
    bf16x8 f2 = *reinterpret_cast<const bf16x8*>(&Bs[2][wc * 16 + (lane & 15)][(lane >> 4) * 8]); \
    aR = __builtin_amdgcn_mfma_f32_16x16x32_bf16(afr, f0, aR, 0, 0, 0);        \
    aZ = __builtin_amdgcn_mfma_f32_16x16x32_bf16(afr, f1, aZ, 0, 0, 0);        \
    ACCN = __builtin_amdgcn_mfma_f32_16x16x32_bf16(afr, f2, ACCN, 0, 0, 0); }

// Depth-2 software pipeline over 32-wide K-chunks; named register sets.
#define GRU_PHASE(KLEN, ALOAD, WP, WLD_, ACCN)                                 \
  { uint2 aP0, aP1;                                                            \
    uint2 b0P0, b1P0, b2P0, b0P1, b1P1, b2P1;                                  \
    ALOAD(0, aP0)                                                              \
    b0P0 = LB3(WP, WLD_, 0, 0); b1P0 = LB3(WP, WLD_, 1, 0); b2P0 = LB3(WP, WLD_, 2, 0); \
    if ((KLEN) > 32) {                                                         \
      ALOAD(32, aP1)                                                           \
      b0P1 = LB3(WP, WLD_, 0, 32); b1P1 = LB3(WP, WLD_, 1, 32); b2P1 = LB3(WP, WLD_, 2, 32); \
    }                                                                          \
    for (int k0 = 0; k0 < (KLEN); k0 += 64) {                                  \
      __syncthreads();                                                         \
      *reinterpret_cast<uint2*>(&Xs[arow][ak]) = aP0;                          \
      *reinterpret_cast<uint2*>(&Bs[0][bn][bk]) = b0P0;                        \
      *reinterpret_cast<uint2*>(&Bs[1][bn][bk]) = b1P0;                        \
      *reinterpret_cast<uint2*>(&Bs[2][bn][bk]) = b2P0;                        \
      if (k0 + 64 < (KLEN)) {                                                  \
        ALOAD(k0 + 64, aP0)                                                    \
        b0P0 = LB3(WP, WLD_, 0, k0 + 64); b1P0 = LB3(WP, WLD_, 1, k0 + 64); b2P0 = LB3(WP, WLD_, 2, k0 + 64); \
      }                                                                        \
      __syncthreads();                                                         \
      GRU_MMA(ACCN)                                                            \
      if (k0 + 32 < (KLEN)) {                                                  \
        __syncthreads();                                                       \
        *reinterpret_cast<uint2*>(&Xs[arow][ak]) = aP1;                        \
        *reinterpret_cast<uint2*>(&Bs[0][bn][bk]) = b0P1;                      \
        *reinterpret_cast<uint2*>(&Bs[1][bn][bk]) = b1P1;                      \
        *reinterpret_cast<uint2*>(&Bs[2][bn][bk]) = b2P1;                      \
        if (k0 + 96 < (KLEN)) {                                                \
          ALOAD(k0 + 96, aP1)                                                  \
          b0P1 = LB3(WP, WLD_, 0, k0 + 96); b1P1 = LB3(WP, WLD_, 1, k0 + 96); b2P1 = LB3(WP, WLD_, 2, k0 + 96); \
        }                                                                      \
        __syncthreads();                                                       \
        GRU_MMA(ACCN)                                                          \
      }                                                                        \
    } }

__global__ __launch_bounds__(256) void gru_k(GruP2 pp)
{
  const GruP p = pp.d[blockIdx.z];
  __shared__ ushort_t Xs[32][40];
  __shared__ ushort_t Bs[3][32][40];
  const int tid = threadIdx.x;
  const int lane = tid & 63, wv = tid >> 6;
  const int wr = wv >> 1, wc = wv & 1;
  const int r0 = blockIdx.x * 32, c0 = blockIdx.y * 32;
  const int arow = tid >> 3, ak = (tid & 7) * 4;
  const int bn = tid >> 3, bk = (tid & 7) * 4;
  f32x4 aR = {}, aZ = {}, aNX = {}, aNH = {};

  if (!p.hz) { GRU_PHASE(HDIM, AL_H, p.Whh, HDIM, aNH) }
  if (p.K0 > 0) {
    if (p.x0b) { GRU_PHASE(p.K0, AL_X0B, p.W0, p.w0ld, aNX) }
    else       { GRU_PHASE(p.K0, AL_X0F, p.W0, p.w0ld, aNX) }
  }
  if (p.K1 > 0) { GRU_PHASE(p.K1, AL_CH, p.W1, p.w1ld, aNX) }

#pragma unroll
  for (int rg = 0; rg < 4; ++rg) {
    int r = r0 + wr * 16 + ((lane >> 4) << 2) + rg;
    int c = c0 + wc * 16 + (lane & 15);
    float sr = aR[rg] + p.bhh[c];
    float sz = aZ[rg] + p.bhh[HDIM + c];
    float nx = aNX[rg];
    float nh = aNH[rg] + p.bhh[2 * HDIM + c];
    if (p.bih) { sr += p.bih[c]; sz += p.bih[HDIM + c]; nx += p.bih[2 * HDIM + c]; }
    if (p.gxf) {
      const float* g = p.gxf + (size_t)r * GG;
      sr += g[c]; sz += g[HDIM + c]; nx += g[2 * HDIM + c];
    }
    if (p.gxb) {
      const ushort_t* g = p.gxb + (size_t)(p.gxros + r) * 1536;
      sr += b2f(g[c]); sz += b2f(g[HDIM + c]); nx += b2f(g[2 * HDIM + c]);
    }
    float rgate = 1.f / (1.f + expf(-sr));
    float zgate = 1.f / (1.f + expf(-sz));
    float ngate = tanhf(nx + rgate * nh);
    float hp = p.hz ? 0.f : p.h_prev[(size_t)r * p.hs + c];
    float hv = (1.f - zgate) * ngate + zgate * hp;
    p.h_out[(size_t)r * p.os + c] = hv;
    if (p.h_out2) p.h_out2[(size_t)r * p.o2s + c] = f2b(hv);
  }
}

// ---------------------------------------------------------------------------
// gx GEMM for enc1: C_bf16[2][4096][1536] = y0b @ W^T + bias. Both dirs in
// one launch (dir = rBase>>12). Tile 64x128, 512 thr.
// ---------------------------------------------------------------------------
__global__ __launch_bounds__(512) void gx_gemm_k(
    const ushort_t* __restrict__ Aarg, const ushort_t* __restrict__ W,
    int ldw, int dirWStride,
    const float* __restrict__ bias, ushort_t* __restrict__ C, int t0, int K)
{
  __shared__ ushort_t As[64][40];
  __shared__ ushort_t Bs[128][40];
  const int tid = threadIdx.x;
  const int lane = tid & 63, wv = tid >> 6;
  const int wr = wv >> 2, wc = wv & 3;
  const int rBase = blockIdx.x * 64, n0 = blockIdx.y * 128;
  const int dir = rBase >> 12;
  const int arow = tid >> 3, ak = (tid & 7) * 4;
  const int bcol = tid >> 2, bk = (tid & 3) * 8;
  int r = rBase + arow;
  int tl = (r >> 8) & 15, b = r & 255;
  int tsrc = (dir == 0) ? (t0 + tl) : (127 - t0 - tl);
  const ushort_t* apB = Aarg + (size_t)b * 131072 + (size_t)tsrc * 1024;
  const ushort_t* wrow = W + (size_t)dir * dirWStride + (size_t)(n0 + bcol) * ldw;
  f32x4 acc[2][2] = {};

  uint2 aC = *reinterpret_cast<const uint2*>(apB + ak);
  uint4 bC = *reinterpret_cast<const uint4*>(wrow + bk);
  for (int k0 = 0; k0 < K; k0 += 32) {
    __syncthreads();
    *reinterpret_cast<uint2*>(&As[arow][ak]) = aC;
    *reinterpret_cast<uint4*>(&Bs[bcol][bk]) = bC;
    if (k0 + 32 < K) {
      aC = *reinterpret_cast<const uint2*>(apB + k0 + 32 + ak);
      bC = *reinterpret_cast<const uint4*>(wrow + k0 + 32 + bk);
    }
    __syncthreads();
    bf16x8 af[2], bf[2];
#pragma unroll
    for (int i = 0; i < 2; ++i)
      af[i] = *reinterpret_cast<const bf16x8*>(&As[wr * 32 + i * 16 + (lane & 15)][(lane >> 4) * 8]);
#pragma unroll
    for (int j = 0; j < 2; ++j)
      bf[j] = *reinterpret_cast<const bf16x8*>(&Bs[wc * 32 + j * 16 + (lane & 15)][(lane >> 4) * 8]);
#pragma unroll
    for (int i = 0; i < 2; ++i)
#pragma unroll
      for (int j = 0; j < 2; ++j)
        acc[i][j] = __builtin_amdgcn_mfma_f32_16x16x32_bf16(af[i], bf[j], acc[i][j], 0, 0, 0);
  }
#pragma unroll
  for (int i = 0; i < 2; ++i)
#pragma unroll
    for (int j = 0; j < 2; ++j)
#pragma unroll
      for (int rg = 0; rg < 4; ++rg) {
        int rr = rBase + wr * 32 + i * 16 + ((lane >> 4) << 2) + rg;
        int cc = n0 + wc * 32 + j * 16 + (lane & 15);
        C[(size_t)rr * 1536 + cc] = f2b(acc[i][j][rg] + bias[dir * 1536 + cc]);
      }
}

// ---------------------------------------------------------------------------
// Decoder emb GEMM: C_bf16[8192][1536] = h1c @ dec0_Wih[:, :512]^T + bih.
// ---------------------------------------------------------------------------
__global__ __launch_bounds__(256) void gemm_demb_k(
    const float* __restrict__ A,
    const ushort_t* __restrict__ W, int ldw,
    const float* __restrict__ bias,
    ushort_t* __restrict__ C)
{
  __shared__ ushort_t As[32][40];
  __shared__ ushort_t Bs[64][40];
  const int tid = threadIdx.x;
  const int lane = tid & 63, wv = tid >> 6;
  const int wr = wv >> 1, wc = wv & 1;
  const int r0 = blockIdx.x * 32, c0 = blockIdx.y * 64;
  const int arow = tid >> 3, ak = (tid & 7) * 4;
  const int bn = tid >> 2, bk = (tid & 3) * 8;
  f32x4 acc[2] = {};
  const float* arowp = A + (size_t)(r0 + arow) * 512;
  const ushort_t* wrow = W + (size_t)(c0 + bn) * ldw;

  uint2 aC = packA(*reinterpret_cast<const float4*>(arowp + ak));
  uint4 bC = *reinterpret_cast<const uint4*>(wrow + bk);
  for (int k0 = 0; k0 < 512; k0 += 32) {
    __syncthreads();
    *reinterpret_cast<uint2*>(&As[arow][ak]) = aC;
    *reinterpret_cast<uint4*>(&Bs[bn][bk]) = bC;
    if (k0 + 32 < 512) {
      aC = packA(*reinterpret_cast<const float4*>(arowp + k0 + 32 + ak));
      bC = *reinterpret_cast<const uint4*>(wrow + k0 + 32 + bk);
    }
    __syncthreads();
    bf16x8 afr = *reinterpret_cast<const bf16x8*>(&As[wr * 16 + (lane & 15)][(lane >> 4) * 8]);
#pragma unroll
    for (int j = 0; j < 2; ++j) {
      bf16x8 bfr = *reinterpret_cast<const bf16x8*>(&Bs[wc * 32 + j * 16 + (lane & 15)][(lane >> 4) * 8]);
      acc[j] = __builtin_amdgcn_mfma_f32_16x16x32_bf16(afr, bfr, acc[j], 0, 0, 0);
    }
  }
#pragma unroll
  for (int j = 0; j < 2; ++j)
#pragma unroll
    for (int rg = 0; rg < 4; ++rg) {
      int r = r0 + wr * 16 + ((lane >> 4) << 2) + rg;
      int c = c0 + wc * 32 + j * 16 + (lane & 15);
      C[(size_t)r * 1536 + c] = f2b(acc[j][rg] + bias[c]);
    }
}

// ---------------------------------------------------------------------------
// Generic MFMA GEMM (f32 A, f32 W cvt on the fly), 32x64 tile.
// ---------------------------------------------------------------------------
__global__ __launch_bounds__(256) void mfma_gemm_k(
    const float* __restrict__ A, int lda,
    const float* __restrict__ W, int ldw,
    const float* __restrict__ bias,
    float* __restrict__ C, int ldc, int N, int K)
{
  __shared__ ushort_t As[32][40];
  __shared__ ushort_t Bs[64][40];
  const int tid = threadIdx.x;
  const int lane = tid & 63, wv = tid >> 6;
  const int wr = wv >> 1, wc = wv & 1;
  const int r0 = blockIdx.x * 32, c0 = blockIdx.y * 64;
  const int arow = tid >> 3, ak = (tid & 7) * 4;
  const int bn = tid >> 2, bk = (tid & 3) * 8;
  f32x4 acc[2] = {};
  const int nOk = (c0 + bn) < N;
  const float* wrow = W + (size_t)(nOk ? (c0 + bn) : 0) * ldw;

  uint2 aC = packA(*reinterpret_cast<const float4*>(A + (size_t)(r0 + arow) * lda + ak));
  uint4 bC;
  {
    float4 v0 = *reinterpret_cast<const float4*>(wrow + bk);
    float4 v1 = *reinterpret_cast<const float4*>(wrow + bk + 4);
    bC = packA8(v0, v1);
  }
  for (int k0 = 0; k0 < K; k0 += 32) {
    __syncthreads();
    *reinterpret_cast<uint2*>(&As[arow][ak]) = aC;
    if (nOk) *reinterpret_cast<uint4*>(&Bs[bn][bk]) = bC;
    else { uint4 z; z.x = z.y = z.z = z.w = 0; *reinterpret_cast<uint4*>(&Bs[bn][bk]) = z; }
    if (k0 + 32 < K) {
      aC = packA(*reinterpret_cast<const float4*>(A + (size_t)(r0 + arow) * lda + k0 + 32 + ak));
      float4 v0 = *reinterpret_cast<const float4*>(wrow + k0 + 32 + bk);
      float4 v1 = *reinterpret_cast<const float4*>(wrow + k0 + 32 + bk + 4);
      bC = packA8(v0, v1);
    }
    __syncthreads();
    bf16x8 afr = *reinterpret_cast<const bf16x8*>(&As[wr * 16 + (lane & 15)][(lane >> 4) * 8]);
#pragma unroll
    for (int j = 0; j < 2; ++j) {
      bf16x8 bfr = *reinterpret_cast<const bf16x8*>(&Bs[wc * 32 + j * 16 + (lane & 15)][(lane >> 4) * 8]);
      acc[j] = __builtin_amdgcn_mfma_f32_16x16x32_bf16(afr, bfr, acc[j], 0, 0, 0);
    }
  }
#pragma unroll
  for (int j = 0; j < 2; ++j)
#pragma unroll
    for (int rg = 0; rg < 4; ++rg) {
      int r = r0 + wr * 16 + ((lane >> 4) << 2) + rg;
      int c = c0 + wc * 32 + j * 16 + (lane & 15);
      if (c < N) C[(size_t)r * ldc + c] = acc[j][rg] + (bias ? bias[c] : 0.f);
    }
}

// ---------------------------------------------------------------------------
// Small elementwise kernels
// ---------------------------------------------------------------------------
__global__ void gather_hidden_k(const ushort_t* __restrict__ y0b,
                                const float* __restrict__ h1f,
                                const float* __restrict__ h1b,
                                float* __restrict__ hidden)
{
  int i = blockIdx.x * 256 + threadIdx.x;
  if (i >= BB * 4 * HDIM) return;
  int b = i >> 11, j = i & 2047;
  float v;
  if (j < 512)       v = b2f(y0b[(size_t)b * 131072 + 127 * 1024 + j]);
  else if (j < 1024) v = b2f(y0b[(size_t)b * 131072 + j]);
  else if (j < 1536) v = h1f[b * 512 + (j - 1024)];
  else               v = h1b[b * 512 + (j - 1536)];
  hidden[i] = v;
}

__global__ void z_k(const float* __restrict__ mu, const float* __restrict__ lv,
                    const float* __restrict__ eps, float* __restrict__ z,
                    float* __restrict__ out_mu, float* __restrict__ out_lv)
{
  int i = blockIdx.x * 256 + threadIdx.x;
  if (i >= BB * HDIM) return;
  float m = mu[i], l = lv[i];
  z[i] = eps[i] * expf(0.5f * l) + m;
  out_mu[i] = m;
  out_lv[i] = l;
}

__global__ void softmax_k(const float* __restrict__ logits,
                          float* __restrict__ out_sm,
                          float* __restrict__ out_lsm)
{
  int q = blockIdx.x;
  int lane = threadIdx.x;
  const float* row = logits + (size_t)q * 96;
  float v0 = row[lane];
  float v1 = (lane < 32) ? row[lane + 64] : -1e30f;
  float m = fmaxf(v0, v1);
#pragma unroll
  for (int o = 32; o; o >>= 1) m = fmaxf(m, __shfl_xor(m, o));
  float e0 = expf(v0 - m);
  float e1 = (lane < 32) ? expf(v1 - m) : 0.f;
  float s = e0 + e1;
#pragma unroll
  for (int o = 32; o; o >>= 1) s += __shfl_xor(s, o);
  float inv = 1.f / s, ls = logf(s);
  int b = (q >> 2) & 255;
  int t = (q >> 10) * 4 + (q & 3);
  size_t base = (size_t)b * TT * 96 + (size_t)t * 96;
  out_sm[base + lane]  = e0 * inv;
  out_lsm[base + lane] = v0 - m - ls;
  if (lane < 32) {
    out_sm[base + lane + 64]  = e1 * inv;
    out_lsm[base + lane + 64] = v1 - m - ls;
  }
}

__global__ void echo_k(const float* __restrict__ in, float* __restrict__ out)
{
  int i = blockIdx.x * 256 + threadIdx.x;
  if (i < BB * TT * NCC) out[i] = in[i];
}

// ---------------------------------------------------------------------------
extern "C" void kernel_launch(void* const* d_in, const int* in_sizes, int n_in,
                              void* d_out, int out_size, void* d_ws, size_t ws_size,
                              hipStream_t stream)
{
  const float* in        = (const float*)d_in[0];
  const float* eps       = (const float*)d_in[2];
  const float* enc0_Wih  = (const float*)d_in[3];
  const float* enc0_Whh  = (const float*)d_in[4];
  const float* enc0_bih  = (const float*)d_in[5];
  const float* enc0_bhh  = (const float*)d_in[6];
  const float* enc1_Wih  = (const float*)d_in[7];
  const float* enc1_Whh  = (const float*)d_in[8];
  const float* enc1_bih  = (const float*)d_in[9];
  const float* enc1_bhh  = (const float*)d_in[10];
  const float* con0_Wih  = (const float*)d_in[11];
  const float* con0_Whh  = (const float*)d_in[12];
  const float* con0_bih  = (const float*)d_in[13];
  const float* con0_bhh  = (const float*)d_in[14];
  const float* con1_Wih  = (const float*)d_in[15];
  const float* con1_Whh  = (const float*)d_in[16];
  const float* con1_bih  = (const float*)d_in[17];
  const float* con1_bhh  = (const float*)d_in[18];
  const float* dec0_Wih  = (const float*)d_in[19];
  const float* dec0_Whh  = (const float*)d_in[20];
  const float* dec0_bih  = (const float*)d_in[21];
  const float* dec0_bhh  = (const float*)d_in[22];
  const float* dec1_Wih  = (const float*)d_in[23];
  const float* dec1_Whh  = (const float*)d_in[24];
  const float* dec1_bih  = (const float*)d_in[25];
  const float* dec1_bhh  = (const float*)d_in[26];
  const float* W_mu      = (const float*)d_in[27];
  const float* b_mu      = (const float*)d_in[28];
  const float* W_lv      = (const float*)d_in[29];
  const float* b_lv      = (const float*)d_in[30];
  const float* W_ci      = (const float*)d_in[31];
  const float* b_ci      = (const float*)d_in[32];
  const float* W_ch      = (const float*)d_in[33];
  const float* b_ch      = (const float*)d_in[34];
  const float* W_out     = (const float*)d_in[35];
  const float* b_out     = (const float*)d_in[36];

  // ---- workspace layout (f32 slots; 33,554,432 = 128 MiB exactly) ----------
  float* ws = (float*)d_ws;
  ushort_t* y0b  = (ushort_t*)ws;                      // [256][128][1024] bf16
  float* e0pp    = ws + 16777216;                      // [2pp][2dir][256][512]
  ushort_t* gxAll = (ushort_t*)(ws + 17301504);        // [2][4096][1536] bf16
  // decoder-phase aliases (y0b/e0pp/gxAll dead):
  float* h0c   = ws;                                   // [32][256][512]
  float* h1c   = ws + 4194304;
  float* d0p[2] = { ws + 8388608,  ws + 12582912 };
  float* d1p[2] = { ws + 16777216, ws + 20971520 };
  // persistent smalls
  float* mu_f  = ws + 26492928;
  float* lv_f  = ws + 26624000;
  float* zz    = ws + 26755072;
  float* ci    = ws + 26886144;
  float* chv   = ws + 26910720;
  float* gx_c0 = ws + 27041792;
  ushort_t* Wb = (ushort_t*)(ws + 27435008);           // 12,238,848 bf16

  ushort_t* wb_e0_Wih = Wb;
  ushort_t* wb_e0_Whh = Wb + 294912;
  ushort_t* wb_e1_Wih = Wb + 1867776;
  ushort_t* wb_e1_Whh = Wb + 5013504;
  ushort_t* wb_c0_Whh = Wb + 6586368;
  ushort_t* wb_c1_Wih = Wb + 7372800;
  ushort_t* wb_c1_Whh = Wb + 8159232;
  ushort_t* wb_d0_Wih = Wb + 8945664;
  ushort_t* wb_d0_Whh = Wb + 9879552;
  ushort_t* wb_d1_Wih = Wb + 10665984;
  ushort_t* wb_d1_Whh = Wb + 11452416;

  float* outp   = (float*)d_out;
  float* out_sm = outp;
  float* out_ls = outp + 3145728;
  float* out_mu = outp + 6291456;
  float* out_lv = outp + 6422528;
  float* out_ec = outp + 6553600;
  // gx_demb scratch occupies out_sm+out_ls regions, dead before softmax_k.
  ushort_t* gx_demb = (ushort_t*)outp;
  // scratch in echo region (dead before echo_k)
  float* fscr = out_ec;
  float* h1f_pp[2] = { fscr,          fscr + 131072 };
  float* h1b_pp[2] = { fscr + 262144, fscr + 393216 };
  float* hidden    = fscr + 524288;                    // [256][2048]
  float* logits_q  = out_ec;                           // decoder: [8192 x 384]

  auto gemmM = [&](const float* A, int lda, const float* W, int ldw, const float* bias,
                   float* C, int ldc, int M, int N, int K) {
    mfma_gemm_k<<<dim3(M / 32, (N + 63) / 64), 256, 0, stream>>>(A, lda, W, ldw, bias, C, ldc, N, K);
  };
  auto gru2 = [&](const GruP& a, const GruP& b, int rows) {
    GruP2 q; q.d[0] = a; q.d[1] = b;
    gru_k<<<dim3(rows / 32, 16, 2), 256, 0, stream>>>(q);
  };
  auto gru1 = [&](const GruP& a, int rows) {
    GruP2 q; q.d[0] = a; q.d[1] = a;
    gru_k<<<dim3(rows / 32, 16, 1), 256, 0, stream>>>(q);
  };

  // ---------------- weight conversion (single launch) ------------------------
  {
    CvtAll ca;
    const float* srcs[11] = { enc0_Wih, enc0_Whh, enc1_Wih, enc1_Whh, con0_Whh,
                              con1_Wih, con1_Whh, dec0_Wih, dec0_Whh, dec1_Wih, dec1_Whh };
    ushort_t* dsts[11] = { wb_e0_Wih, wb_e0_Whh, wb_e1_Wih, wb_e1_Whh, wb_c0_Whh,
                           wb_c1_Wih, wb_c1_Whh, wb_d0_Wih, wb_d0_Whh, wb_d1_Wih, wb_d1_Whh };
    int ns[11] = { 294912, 1572864, 3145728, 1572864, 786432,
                   786432, 786432, 933888, 786432, 786432, 786432 };
    for (int e = 0; e < 11; ++e) { ca.s[e] = srcs[e]; ca.d[e] = dsts[e]; ca.n4[e] = ns[e] / 4; }
    cvt_all_k<<<dim3(3072, 1, 11), 256, 0, stream>>>(ca);
  }

  // ---------------- encoder layer 0 (per-step, inline x) ---------------------
  for (int t = 0; t < TT; ++t) {
    int tr = TT - 1 - t;
    GruP f = {};
    f.hz = (t == 0);
    f.h_prev = e0pp + (size_t)((t + 1) & 1) * 262144; f.hs = 512;
    f.x0f = in + (size_t)t * 96; f.x0s = 12288; f.W0 = wb_e0_Wih; f.w0ld = 96; f.K0 = 96;
    f.Whh = wb_e0_Whh; f.bih = enc0_bih; f.bhh = enc0_bhh;
    f.h_out = e0pp + (size_t)(t & 1) * 262144; f.os = 512;
    f.h_out2 = y0b + (size_t)t * 1024; f.o2s = 131072;
    GruP bd = {};
    bd.hz = (t == 0);
    bd.h_prev = e0pp + (size_t)((t + 1) & 1) * 262144 + 131072; bd.hs = 512;
    bd.x0f = in + (size_t)tr * 96; bd.x0s = 12288;
    bd.W0 = wb_e0_Wih + 147456; bd.w0ld = 96; bd.K0 = 96;
    bd.Whh = wb_e0_Whh + 786432; bd.bih = enc0_bih + GG; bd.bhh = enc0_bhh + GG;
    bd.h_out = e0pp + (size_t)(t & 1) * 262144 + 131072; bd.os = 512;
    bd.h_out2 = y0b + (size_t)tr * 1024 + 512; bd.o2s = 131072;
    gru2(f, bd, BB);
  }

  // ---------------- encoder layer 1 (fused-dir gx + per-step) ----------------
  for (int ch = 0; ch < 8; ++ch) {
    int t0 = ch * 16;
    gx_gemm_k<<<dim3(128, 12), 512, 0, stream>>>(
        y0b, wb_e1_Wih, 1024, 1572864, enc1_bih, gxAll, t0, 1024);
    for (int tl = 0; tl < 16; ++tl) {
      int t = t0 + tl;
      GruP f = {};
      f.hz = (t == 0);
      f.h_prev = h1f_pp[(t + 1) & 1]; f.hs = 512;
      f.Whh = wb_e1_Whh; f.bhh = enc1_bhh;
      f.gxb = gxAll; f.gxros = tl * 256;
      f.h_out = h1f_pp[t & 1]; f.os = 512;
      GruP bd = {};
      bd.hz = (t == 0);
      bd.h_prev = h1b_pp[(t + 1) & 1]; bd.hs = 512;
      bd.Whh = wb_e1_Whh + 786432; bd.bhh = enc1_bhh + GG;
      bd.gxb = gxAll + 6291456; bd.gxros = tl * 256;
      bd.h_out = h1b_pp[t & 1]; bd.os = 512;
      gru2(f, bd, BB);
    }
  }

  // ---------------- latent ----------------------------------------------------
  gather_hidden_k<<<2048, 256, 0, stream>>>(y0b, h1f_pp[1], h1b_pp[1], hidden);
  gemmM(hidden, 2048, W_mu, 2048, b_mu, mu_f, 512, BB, 512, 2048);
  gemmM(hidden, 2048, W_lv, 2048, b_lv, lv_f, 512, BB, 512, 2048);
  z_k<<<512, 256, 0, stream>>>(mu_f, lv_f, eps, zz, out_mu, out_lv);
  gemmM(zz, 512, W_ci, 512, b_ci, ci, 96, BB, 96, 512);
  gemmM(zz, 512, W_ch, 512, b_ch, chv, 512, BB, 512, 512);
  gemmM(ci, 96, con0_Wih, 96, con0_bih, gx_c0, GG, BB, GG, 96);

  // ---------------- conductor (fused: 33 launches) ---------------------------
  auto c0desc = [&](int bar) {
    GruP c0 = {};
    c0.h_prev = (bar == 0) ? chv : h0c + (size_t)(bar - 1) * 131072; c0.hs = 512;
    c0.gxf = gx_c0;
    c0.Whh = wb_c0_Whh; c0.bhh = con0_bhh;
    c0.h_out = h0c + (size_t)bar * 131072; c0.os = 512;
    return c0;
  };
  auto c1desc = [&](int bar) {
    GruP c1 = {};
    c1.h_prev = (bar == 0) ? chv : h1c + (size_t)(bar - 1) * 131072; c1.hs = 512;
    c1.x0f = h0c + (size_t)bar * 131072; c1.x0s = 512;
    c1.W0 = wb_c1_Wih; c1.w0ld = 512; c1.K0 = 512;
    c1.Whh = wb_c1_Whh; c1.bih = con1_bih; c1.bhh = con1_bhh;
    c1.h_out = h1c + (size_t)bar * 131072; c1.os = 512;
    return c1;
  };
  gru1(c0desc(0), BB);
  for (int bar = 1; bar < NBB; ++bar) gru2(c0desc(bar), c1desc(bar - 1), BB);
  gru1(c1desc(NBB - 1), BB);

  // ---------------- decoder: emb-proj hoisted, d0(s) || d1(s-1) fused --------
  gemm_demb_k<<<dim3(256, 24), 256, 0, stream>>>(h1c, wb_d0_Wih, 608, dec0_bih, gx_demb);
  const int R = NBB * BB;
  auto d0desc = [&](int s) {
    GruP d0 = {};
    d0.h_prev = (s == 0) ? h0c : d0p[(s - 1) & 1]; d0.hs = 512;
    d0.x1f = in; d0.x1sp = s; d0.W1 = wb_d0_Wih + 512; d0.w1ld = 608; d0.K1 = 96;
    d0.gxb = gx_demb; d0.gxros = 0;
    d0.Whh = wb_d0_Whh; d0.bhh = dec0_bhh;
    d0.h_out = d0p[s & 1]; d0.os = 512;
    return d0;
  };
  auto d1desc = [&](int s) {
    GruP d1 = {};
    d1.h_prev = (s == 0) ? h1c : d1p[(s - 1) & 1]; d1.hs = 512;
    d1.x0f = d0p[s & 1]; d1.x0s = 512; d1.W0 = wb_d1_Wih; d1.w0ld = 512; d1.K0 = 512;
    d1.Whh = wb_d1_Whh; d1.bih = dec1_bih; d1.bhh = dec1_bhh;
    d1.h_out = d1p[s & 1]; d1.os = 512;
    return d1;
  };
  gru1(d0desc(0), R);
  for (int s = 1; s < CPBB; ++s) {
    gru2(d0desc(s), d1desc(s - 1), R);
    gemmM(d1p[(s - 1) & 1], 512, W_out, 512, b_out, logits_q + (size_t)(s - 1) * 96, 384, R, 96, 512);
  }
  gru1(d1desc(CPBB - 1), R);
  gemmM(d1p[(CPBB - 1) & 1], 512, W_out, 512, b_out, logits_q + (size_t)(CPBB - 1) * 96, 384, R, 96, 512);

  // ---------------- softmax + echo --------------------------------------------
  softmax_k<<<NBB * BB * CPBB, 64, 0, stream>>>(logits_q, out_sm, out_ls);
  echo_k<<<12288, 256, 0, stream>>>(in, out_ec);
}